// Round 5
// baseline (174.230 us; speedup 1.0000x reference)
//
#include <hip/hip_runtime.h>
#include <cfloat>
#include <math.h>

#define K_EMB 512
#define CDIM  64
#define HW    4096        // 64*64 spatial per batch
#define NPOS  131072      // 32*64*64 rows
#define NELEM 8388608     // NPOS*CDIM
#define RPB   256         // rows per block
#define NBLK  (NPOS / RPB)   // 512 blocks -> 2/CU, one residency round
#define RPW   64          // rows per wave (4 A-tiles) -> 4 waves/block

typedef __attribute__((ext_vector_type(8))) short short8;
typedef __attribute__((ext_vector_type(4))) float float4v;

// ws layout: [0,32)        float lossAcc[8]   (atomic accumulators)
//            [2048,4096)   int counts[512]
//            [4096,69632)  unsigned cbBg[512*32]  bf16 codebook, PRE-SWIZZLED
//            [69632,71680) float cn1g[512]        ||c||^2 + 1

__device__ inline unsigned short f2bf(float f) {          // RTNE fp32->bf16
    unsigned u = __builtin_bit_cast(unsigned, f);
    unsigned r = u + 0x7FFFu + ((u >> 16) & 1u);
    return (unsigned short)(r >> 16);
}
__device__ inline unsigned umin2(unsigned a, unsigned b) { return a < b ? a : b; }

// One-time prep (also zeroes counts + lossAcc; no memset dispatch). Packs the
// codebook to bf16 at the group-XOR-swizzled offsets so vq_main stages
// linearly with global_load_lds while n-loop/epilogue reads stay correct.
__global__ __launch_bounds__(512) void cb_prep(const float* __restrict__ cbf,
                                               unsigned* __restrict__ cbBg,
                                               float* __restrict__ cn1g,
                                               int* __restrict__ counts,
                                               float* __restrict__ lossAcc) {
    int t = threadIdx.x;
    if (blockIdx.x == 0) {
        counts[t] = 0;                             // capture-safe zero
        if (t < 8) lossAcc[t] = 0.f;
    }
    int gi = blockIdx.x * 512 + t;                 // [0, 4096)
    int e = gi >> 3, g = gi & 7;
    float4 x0 = *(const float4*)(cbf + (size_t)gi * 8);
    float4 x1 = *(const float4*)(cbf + (size_t)gi * 8 + 4);
    float s = 0.f;
    s = fmaf(x0.x, x0.x, s); s = fmaf(x0.y, x0.y, s);
    s = fmaf(x0.z, x0.z, s); s = fmaf(x0.w, x0.w, s);
    s = fmaf(x1.x, x1.x, s); s = fmaf(x1.y, x1.y, s);
    s = fmaf(x1.z, x1.z, s); s = fmaf(x1.w, x1.w, s);
    unsigned d0 = (unsigned)f2bf(x0.x) | ((unsigned)f2bf(x0.y) << 16);
    unsigned d1 = (unsigned)f2bf(x0.z) | ((unsigned)f2bf(x0.w) << 16);
    unsigned d2 = (unsigned)f2bf(x1.x) | ((unsigned)f2bf(x1.y) << 16);
    unsigned d3 = (unsigned)f2bf(x1.z) | ((unsigned)f2bf(x1.w) << 16);
    *(uint4*)(&cbBg[e * 32 + ((g ^ (e & 7)) * 4)]) = make_uint4(d0, d1, d2, d3);
    s += __shfl_xor(s, 1); s += __shfl_xor(s, 2); s += __shfl_xor(s, 4);
    if ((t & 7) == 0) cn1g[e] = s + 1.0f;
}

#if __has_builtin(__builtin_amdgcn_global_load_lds)
typedef const __attribute__((address_space(1))) unsigned gu_t;
typedef __attribute__((address_space(3))) unsigned lu_t;
#define HAVE_GLD_LDS 1
#else
#define HAVE_GLD_LDS 0
#endif

// R14: R4 skeleton, waves fully independent after the single staging barrier.
// No hist (direct device-scope counts atomics), no lossW (global float
// atomics, 8 spread slots), per-wave epilogue (lane = own row, bidx exchange
// is same-wave LDS -> no barrier). Two vmcnt(0)+s_barrier drains removed;
// waves/blocks self-pipeline: one wave's stores overlap another's n-loop.
// Indices/out numerics byte-identical to R4.
__global__ __launch_bounds__(256, 2) __attribute__((amdgpu_waves_per_eu(2, 2)))
void vq_main(const float* __restrict__ z,
             const unsigned* __restrict__ cbBg,
             const float* __restrict__ cn1g,
             float* __restrict__ out,
             int* __restrict__ counts,
             float* __restrict__ lossAcc) {
    __shared__ unsigned cbB[K_EMB * 32];   // 64 KB, swizzled content (copied linearly)
    __shared__ float    cn1L[K_EMB];       // 2 KB
    __shared__ int      bidxL[RPB];        // 1 KB (per-wave disjoint regions)

    int t = threadIdx.x;
    int lane = t & 63, w = t >> 6;         // w = 0..3
    int l15 = lane & 15, quad = lane >> 4;

    int p0  = blockIdx.x * RPB;            // 256 | 4096 -> single batch per block
    int b   = p0 >> 12;
    int hwb = p0 & 4095;
    const float* zb = z + (size_t)b * (CDIM * HW);
    float* ob = out + (size_t)b * (CDIM * HW);

    // stage codebook: linear LDS dest (wave-uniform base + lane*16), swizzle
    // pre-applied in cbBg. 16 x dwordx4 with 256 threads = 64 KB.
#if HAVE_GLD_LDS
    #pragma unroll
    for (int it = 0; it < 16; ++it) {
        int d = (it * 256 + t) * 4;
        __builtin_amdgcn_global_load_lds((gu_t*)(cbBg + d), (lu_t*)(&cbB[d]), 16, 0, 0);
    }
    #pragma unroll
    for (int it = 0; it < 2; ++it) {
        int d = it * 256 + t;
        __builtin_amdgcn_global_load_lds((gu_t*)((const unsigned*)cn1g + d),
                                         (lu_t*)((unsigned*)&cn1L[d]), 4, 0, 0);
    }
#else
    #pragma unroll
    for (int it = 0; it < 16; ++it) {
        int d = (it * 256 + t) * 4;
        *(uint4*)(&cbB[d]) = *(const uint4*)(cbBg + d);
    }
    cn1L[t] = cn1g[t];  cn1L[t + 256] = cn1g[t + 256];
#endif

    // z A-frags: 64 rows/wave = 4 tiles; loads overlap the LDS staging in the
    // vmcnt queue; the single barrier drains both.
    // A[m=l15][k=quad*8+j], c = kt*32 + quad*8 + j, hw = hwb + w*64 + T*16 + l15
    short8 afrag[4][2];
    float zsq = 0.f;
    int hw0 = hwb + w * RPW + l15;
    #pragma unroll
    for (int T = 0; T < 4; ++T)
        #pragma unroll
        for (int kt = 0; kt < 2; ++kt) {
            short8 f;
            #pragma unroll
            for (int j = 0; j < 8; ++j) {
                float v = zb[(size_t)(kt * 32 + quad * 8 + j) * HW + hw0 + T * 16];
                zsq = fmaf(v, v, zsq);
                f[j] = (short)f2bf(v);
            }
            afrag[T][kt] = f;
        }
    __syncthreads();           // the ONLY barrier: staging + z both drained

    // n-loop: 32 entry-tiles, per-wave rotated start (min is order-independent:
    // index lives in the key's low bits). 2 swizzled ds_read_b128 + 1
    // ds_read_b32 feed 8 MFMAs. key = fmaf(-2, acc, cn1), R8-proven.
    unsigned um[4][4];
    #pragma unroll
    for (int T = 0; T < 4; ++T)
        #pragma unroll
        for (int i = 0; i < 4; ++i) um[T][i] = 0xFFFFFFFFu;

    int ex = l15 & 7;                      // == e & 7 for e = nt*16 + l15
    #pragma unroll 4
    for (int q = 0; q < 32; ++q) {
        int nt = (q + (w << 3)) & 31;
        int e = nt * 16 + l15;
        short8 b0 = __builtin_bit_cast(short8, *(const uint4*)&cbB[e * 32 + ((quad ^ ex) * 4)]);
        short8 b1 = __builtin_bit_cast(short8, *(const uint4*)&cbB[e * 32 + (((4 + quad) ^ ex) * 4)]);
        float  cn = cn1L[e];
        #pragma unroll
        for (int T = 0; T < 4; ++T) {
            float4v acc = {0.f, 0.f, 0.f, 0.f};
            acc = __builtin_amdgcn_mfma_f32_16x16x32_bf16(afrag[T][0], b0, acc, 0, 0, 0);
            acc = __builtin_amdgcn_mfma_f32_16x16x32_bf16(afrag[T][1], b1, acc, 0, 0, 0);
            #pragma unroll
            for (int i = 0; i < 4; ++i) {  // key in (0.5,2): bits monotone
                float key = fmaf(-2.f, acc[i], cn);
                unsigned u = (__builtin_bit_cast(unsigned, key) & 0xFFFFFE00u) | (unsigned)e;
                um[T][i] = umin2(um[T][i], u);
            }
        }
    }

    // finalize: butterfly-min over 16 entry-lanes; row_in_wave = T*16+quad*4+i.
    // Winning lane does the global counts atomic directly (no hist/flush).
    float lsum = zsq;
    #pragma unroll
    for (int T = 0; T < 4; ++T)
        #pragma unroll
        for (int i = 0; i < 4; ++i) {
            unsigned u = um[T][i];
            u = umin2(u, (unsigned)__shfl_xor((int)u, 1));
            u = umin2(u, (unsigned)__shfl_xor((int)u, 2));
            u = umin2(u, (unsigned)__shfl_xor((int)u, 4));
            u = umin2(u, (unsigned)__shfl_xor((int)u, 8));
            if (l15 == 0) {
                int idx = (int)(u & 511u);
                bidxL[w * RPW + T * 16 + quad * 4 + i] = idx;
                atomicAdd(&counts[idx], 1);
                lsum += __builtin_bit_cast(float, u & 0xFFFFFE00u) - 1.0f;  // ||c||^2-2z.c
            }
        }
    // NO barrier: bidxL region [w*64, w*64+64) is same-wave RAW (lgkmcnt-ordered)

    // epilogue (per-wave): lane = row_in_wave, q unpacked from LDS bf16
    // codebook. out = q (straight-through); bf16 rounding <=4e-6 abs error.
    // Stores 64-lane coalesced (rows contiguous along hw).
    {
        int idx = bidxL[w * RPW + lane];
        int exo = idx & 7;
        float* op = ob + hwb + w * RPW + lane;
        #pragma unroll
        for (int g = 0; g < 8; ++g) {
            uint4 dw = *(const uint4*)&cbB[idx * 32 + ((g ^ exo) * 4)];
            op[(size_t)(g * 8 + 0) * HW] = __builtin_bit_cast(float, dw.x << 16);
            op[(size_t)(g * 8 + 1) * HW] = __builtin_bit_cast(float, dw.x & 0xFFFF0000u);
            op[(size_t)(g * 8 + 2) * HW] = __builtin_bit_cast(float, dw.y << 16);
            op[(size_t)(g * 8 + 3) * HW] = __builtin_bit_cast(float, dw.y & 0xFFFF0000u);
            op[(size_t)(g * 8 + 4) * HW] = __builtin_bit_cast(float, dw.z << 16);
            op[(size_t)(g * 8 + 5) * HW] = __builtin_bit_cast(float, dw.z & 0xFFFF0000u);
            op[(size_t)(g * 8 + 6) * HW] = __builtin_bit_cast(float, dw.w << 16);
            op[(size_t)(g * 8 + 7) * HW] = __builtin_bit_cast(float, dw.w & 0xFFFF0000u);
        }
    }

    // loss: wave reduce -> one global float atomic per wave (8 spread slots;
    // FP order jitter only affects the loss scalar, tolerance is huge).
    #pragma unroll
    for (int m = 1; m < 64; m <<= 1) lsum += __shfl_xor(lsum, m);
    if (lane == 0) atomicAdd(&lossAcc[(blockIdx.x + w) & 7], lsum);
}

__global__ __launch_bounds__(512) void vq_final(const int* __restrict__ counts,
                                                const float* __restrict__ lossAcc,
                                                float* __restrict__ out_scalars) {
    __shared__ float re[512];
    int k = threadIdx.x;
    float pr = (float)counts[k] / (float)NPOS;
    re[k] = pr * logf(pr + 1e-10f);
    __syncthreads();
    for (int s = 256; s > 0; s >>= 1) {
        if (k < s) re[k] += re[k + s];
        __syncthreads();
    }
    if (k == 0) {
        float rl = 0.f;
        #pragma unroll
        for (int j = 0; j < 8; ++j) rl += lossAcc[j];
        float m = rl / (float)NELEM;
        out_scalars[0] = 1.25f * m;        // vq_loss + 0.25*commitment (identical means)
        out_scalars[1] = expf(-re[0]);     // perplexity
    }
}

extern "C" void kernel_launch(void* const* d_in, const int* in_sizes, int n_in,
                              void* d_out, int out_size, void* d_ws, size_t ws_size,
                              hipStream_t stream) {
    const float* z  = (const float*)d_in[0];
    const float* cb = (const float*)d_in[1];
    float* out = (float*)d_out;

    float*    lossAcc = (float*)d_ws;                          // 32 B
    int*      counts  = (int*)((char*)d_ws + 2048);            // 2 KB
    unsigned* cbBg    = (unsigned*)((char*)d_ws + 4096);       // 64 KB
    float*    cn1g    = (float*)((char*)d_ws + 4096 + 65536);  // 2 KB

    cb_prep<<<8, 512, 0, stream>>>(cb, cbBg, cn1g, counts, lossAcc);
    vq_main<<<NBLK, 256, 0, stream>>>(z, cbBg, cn1g, out, counts, lossAcc);
    vq_final<<<1, 512, 0, stream>>>(counts, lossAcc, out + NELEM);
}

// Round 6
// 103.715 us; speedup vs baseline: 1.6799x; 1.6799x over previous
//
#include <hip/hip_runtime.h>
#include <cfloat>
#include <math.h>

#define K_EMB 512
#define CDIM  64
#define HW    4096        // 64*64 spatial per batch
#define NPOS  131072      // 32*64*64 rows
#define NELEM 8388608     // NPOS*CDIM
#define RPB   256         // rows per block
#define NBLK  (NPOS / RPB)   // 512 blocks -> 2/CU, one residency round
#define RPW   64          // rows per wave (4 A-tiles) -> 4 waves/block

typedef __attribute__((ext_vector_type(8))) short short8;
typedef __attribute__((ext_vector_type(4))) float float4v;

// ws layout: [0,2048)      float lossArr[512]
//            [2048,4096)   int counts[512]
//            [4096,69632)  unsigned cbBg[512*32]  bf16 codebook, PRE-SWIZZLED
//            [69632,71680) float cn1g[512]        ||c||^2 + 1
//
// R15 = exact revert to R4 (102.8us, best verified). R5's lesson: direct
// device-scope atomics from every wave onto few lines (counts: 32 lines,
// loss: 8) cause cross-XCD cacheline ping-pong -> VMEM backpressure ->
// vq_main 24->100us. Third regression in this class (R1 fence, R2 L2-direct,
// R5 atomics). Per-block LDS hist + one rotated flush is the proven pattern.

__device__ inline unsigned short f2bf(float f) {          // RTNE fp32->bf16
    unsigned u = __builtin_bit_cast(unsigned, f);
    unsigned r = u + 0x7FFFu + ((u >> 16) & 1u);
    return (unsigned short)(r >> 16);
}
__device__ inline unsigned umin2(unsigned a, unsigned b) { return a < b ? a : b; }

// One-time prep (also zeroes counts; no memset dispatch). Packs codebook to
// bf16 at the group-XOR-swizzled offsets so vq_main stages linearly with
// global_load_lds while n-loop/epilogue reads stay swizzle-correct.
__global__ __launch_bounds__(512) void cb_prep(const float* __restrict__ cbf,
                                               unsigned* __restrict__ cbBg,
                                               float* __restrict__ cn1g,
                                               int* __restrict__ counts) {
    int t = threadIdx.x;
    if (blockIdx.x == 0) counts[t] = 0;            // capture-safe zero
    int gi = blockIdx.x * 512 + t;                 // [0, 4096)
    int e = gi >> 3, g = gi & 7;
    float4 x0 = *(const float4*)(cbf + (size_t)gi * 8);
    float4 x1 = *(const float4*)(cbf + (size_t)gi * 8 + 4);
    float s = 0.f;
    s = fmaf(x0.x, x0.x, s); s = fmaf(x0.y, x0.y, s);
    s = fmaf(x0.z, x0.z, s); s = fmaf(x0.w, x0.w, s);
    s = fmaf(x1.x, x1.x, s); s = fmaf(x1.y, x1.y, s);
    s = fmaf(x1.z, x1.z, s); s = fmaf(x1.w, x1.w, s);
    unsigned d0 = (unsigned)f2bf(x0.x) | ((unsigned)f2bf(x0.y) << 16);
    unsigned d1 = (unsigned)f2bf(x0.z) | ((unsigned)f2bf(x0.w) << 16);
    unsigned d2 = (unsigned)f2bf(x1.x) | ((unsigned)f2bf(x1.y) << 16);
    unsigned d3 = (unsigned)f2bf(x1.z) | ((unsigned)f2bf(x1.w) << 16);
    *(uint4*)(&cbBg[e * 32 + ((g ^ (e & 7)) * 4)]) = make_uint4(d0, d1, d2, d3);
    s += __shfl_xor(s, 1); s += __shfl_xor(s, 2); s += __shfl_xor(s, 4);
    if ((t & 7) == 0) cn1g[e] = s + 1.0f;
}

#if __has_builtin(__builtin_amdgcn_global_load_lds)
typedef const __attribute__((address_space(1))) unsigned gu_t;
typedef __attribute__((address_space(3))) unsigned lu_t;
#define HAVE_GLD_LDS 1
#else
#define HAVE_GLD_LDS 0
#endif

// 4 waves x 64 rows/wave: each B-frag ds_read feeds 4 A-tiles (half the
// per-CU n-loop LDS traffic of the 8x32 form); epilogue gathers q from the
// LDS bf16 codebook (random-idx L1 64-line gather eliminated; |q|<=1/512 so
// bf16 out error <=4e-6, far under threshold). Indices/loss byte-stable.
__global__ __launch_bounds__(256, 2) __attribute__((amdgpu_waves_per_eu(2, 2)))
void vq_main(const float* __restrict__ z,
             const unsigned* __restrict__ cbBg,
             const float* __restrict__ cn1g,
             float* __restrict__ out,
             int* __restrict__ counts,
             float* __restrict__ lossArr) {
    __shared__ unsigned cbB[K_EMB * 32];   // 64 KB, swizzled content (copied linearly)
    __shared__ float    cn1L[K_EMB];       // 2 KB
    __shared__ int      hist[K_EMB];       // 2 KB
    __shared__ int      bidxL[RPB];        // 1 KB
    __shared__ float    lossW[4];

    int t = threadIdx.x;
    int lane = t & 63, w = t >> 6;         // w = 0..3
    int l15 = lane & 15, quad = lane >> 4;

    int p0  = blockIdx.x * RPB;            // 256 | 4096 -> single batch per block
    int b   = p0 >> 12;
    int hwb = p0 & 4095;
    const float* zb = z + (size_t)b * (CDIM * HW);
    float* ob = out + (size_t)b * (CDIM * HW);

    hist[t] = 0;  hist[t + 256] = 0;

    // stage codebook: linear LDS dest (wave-uniform base + lane*16), swizzle
    // pre-applied in cbBg. 16 x dwordx4 with 256 threads = 64 KB.
#if HAVE_GLD_LDS
    #pragma unroll
    for (int it = 0; it < 16; ++it) {
        int d = (it * 256 + t) * 4;
        __builtin_amdgcn_global_load_lds((gu_t*)(cbBg + d), (lu_t*)(&cbB[d]), 16, 0, 0);
    }
    #pragma unroll
    for (int it = 0; it < 2; ++it) {
        int d = it * 256 + t;
        __builtin_amdgcn_global_load_lds((gu_t*)((const unsigned*)cn1g + d),
                                         (lu_t*)((unsigned*)&cn1L[d]), 4, 0, 0);
    }
#else
    #pragma unroll
    for (int it = 0; it < 16; ++it) {
        int d = (it * 256 + t) * 4;
        *(uint4*)(&cbB[d]) = *(const uint4*)(cbBg + d);
    }
    cn1L[t] = cn1g[t];  cn1L[t + 256] = cn1g[t + 256];
#endif

    // z A-frags: 64 rows/wave = 4 tiles. HBM/L3 loads + zsq + pack overlap the
    // LDS staging in the vmcnt queue; one barrier drains both.
    // A[m=l15][k=quad*8+j], c = kt*32 + quad*8 + j, hw = hwb + w*64 + T*16 + l15
    short8 afrag[4][2];
    float zsq = 0.f;
    int hw0 = hwb + w * RPW + l15;
    #pragma unroll
    for (int T = 0; T < 4; ++T)
        #pragma unroll
        for (int kt = 0; kt < 2; ++kt) {
            short8 f;
            #pragma unroll
            for (int j = 0; j < 8; ++j) {
                float v = zb[(size_t)(kt * 32 + quad * 8 + j) * HW + hw0 + T * 16];
                zsq = fmaf(v, v, zsq);
                f[j] = (short)f2bf(v);
            }
            afrag[T][kt] = f;
        }
    __syncthreads();           // compiler emits vmcnt(0): staging + z both done

    // n-loop: 32 entry-tiles. 2 swizzled ds_read_b128 + 1 ds_read_b32 feed
    // 8 MFMAs (4 A-tiles). R8-proven numerics: acc = z.c, key = fmaf(-2,acc,cn1).
    unsigned um[4][4];
    #pragma unroll
    for (int T = 0; T < 4; ++T)
        #pragma unroll
        for (int i = 0; i < 4; ++i) um[T][i] = 0xFFFFFFFFu;

    int ex = l15 & 7;                      // == e & 7 for e = nt*16 + l15
    #pragma unroll 2
    for (int nt = 0; nt < 32; ++nt) {
        int e = nt * 16 + l15;
        short8 b0 = __builtin_bit_cast(short8, *(const uint4*)&cbB[e * 32 + ((quad ^ ex) * 4)]);
        short8 b1 = __builtin_bit_cast(short8, *(const uint4*)&cbB[e * 32 + (((4 + quad) ^ ex) * 4)]);
        float  cn = cn1L[e];
        #pragma unroll
        for (int T = 0; T < 4; ++T) {
            float4v acc = {0.f, 0.f, 0.f, 0.f};
            acc = __builtin_amdgcn_mfma_f32_16x16x32_bf16(afrag[T][0], b0, acc, 0, 0, 0);
            acc = __builtin_amdgcn_mfma_f32_16x16x32_bf16(afrag[T][1], b1, acc, 0, 0, 0);
            #pragma unroll
            for (int i = 0; i < 4; ++i) {  // key in (0.5,2): bits monotone
                float key = fmaf(-2.f, acc[i], cn);
                unsigned u = (__builtin_bit_cast(unsigned, key) & 0xFFFFFE00u) | (unsigned)e;
                um[T][i] = umin2(um[T][i], u);
            }
        }
    }

    // finalize: reduce each um over 16 entry-lanes; row = w*64 + T*16 + quad*4 + i.
    float lsum = zsq;
    #pragma unroll
    for (int T = 0; T < 4; ++T)
        #pragma unroll
        for (int i = 0; i < 4; ++i) {
            unsigned u = um[T][i];
            u = umin2(u, (unsigned)__shfl_xor((int)u, 1));
            u = umin2(u, (unsigned)__shfl_xor((int)u, 2));
            u = umin2(u, (unsigned)__shfl_xor((int)u, 4));
            u = umin2(u, (unsigned)__shfl_xor((int)u, 8));
            if (l15 == 0) {
                int idx = (int)(u & 511u);
                bidxL[w * RPW + T * 16 + quad * 4 + i] = idx;
                atomicAdd(&hist[idx], 1);
                lsum += __builtin_bit_cast(float, u & 0xFFFFFE00u) - 1.0f;  // ||c||^2-2z.c
            }
        }
    __syncthreads();

    // epilogue: 1 thread/row, q unpacked from the LDS bf16 codebook (swizzled
    // groups, random idx -> banks spread by idx&7). out = q exactly (straight-
    // through); bf16 rounding of q adds <=4e-6 abs error. Stores 64-lane coalesced.
    {
        int idx = bidxL[t];
        int exo = idx & 7;
        float* op = ob + hwb + t;
        #pragma unroll
        for (int g = 0; g < 8; ++g) {
            uint4 dw = *(const uint4*)&cbB[idx * 32 + ((g ^ exo) * 4)];
            op[(size_t)(g * 8 + 0) * HW] = __builtin_bit_cast(float, dw.x << 16);
            op[(size_t)(g * 8 + 1) * HW] = __builtin_bit_cast(float, dw.x & 0xFFFF0000u);
            op[(size_t)(g * 8 + 2) * HW] = __builtin_bit_cast(float, dw.y << 16);
            op[(size_t)(g * 8 + 3) * HW] = __builtin_bit_cast(float, dw.y & 0xFFFF0000u);
            op[(size_t)(g * 8 + 4) * HW] = __builtin_bit_cast(float, dw.z << 16);
            op[(size_t)(g * 8 + 5) * HW] = __builtin_bit_cast(float, dw.z & 0xFFFF0000u);
            op[(size_t)(g * 8 + 6) * HW] = __builtin_bit_cast(float, dw.w << 16);
            op[(size_t)(g * 8 + 7) * HW] = __builtin_bit_cast(float, dw.w & 0xFFFF0000u);
        }
    }

    // counts flush, rotated start line (hist final since barrier above).
    // Per-block aggregation + rotation keeps cross-XCD line contention low
    // -- the R5 direct-atomic variant was 4x slower.
    #pragma unroll
    for (int rep = 0; rep < 2; ++rep) {
        int k = (t + rep * 256 + blockIdx.x * 16) & 511;
        int hv = hist[k];
        if (hv) atomicAdd(&counts[k], hv);
    }

    // loss: wave reduce -> lossW -> one store per block
    #pragma unroll
    for (int m = 1; m < 64; m <<= 1) lsum += __shfl_xor(lsum, m);
    if (lane == 0) lossW[w] = lsum;
    __syncthreads();
    if (t == 0) {
        float s = 0.f;
        #pragma unroll
        for (int j = 0; j < 4; ++j) s += lossW[j];
        lossArr[blockIdx.x] = s;
    }
}

__global__ __launch_bounds__(512) void vq_final(const int* __restrict__ counts,
                                                const float* __restrict__ lossArr,
                                                float* __restrict__ out_scalars) {
    __shared__ float re[512];
    __shared__ float rl[512];
    int k = threadIdx.x;
    float pr = (float)counts[k] / (float)NPOS;
    re[k] = pr * logf(pr + 1e-10f);
    rl[k] = lossArr[k];                    // NBLK == 512
    __syncthreads();
    for (int s = 256; s > 0; s >>= 1) {
        if (k < s) { re[k] += re[k + s]; rl[k] += rl[k + s]; }
        __syncthreads();
    }
    if (k == 0) {
        float m = rl[0] / (float)NELEM;
        out_scalars[0] = 1.25f * m;        // vq_loss + 0.25*commitment (identical means)
        out_scalars[1] = expf(-re[0]);     // perplexity
    }
}

extern "C" void kernel_launch(void* const* d_in, const int* in_sizes, int n_in,
                              void* d_out, int out_size, void* d_ws, size_t ws_size,
                              hipStream_t stream) {
    const float* z  = (const float*)d_in[0];
    const float* cb = (const float*)d_in[1];
    float* out = (float*)d_out;

    float*    lossArr = (float*)d_ws;                          // 2 KB
    int*      counts  = (int*)((char*)d_ws + 2048);            // 2 KB
    unsigned* cbBg    = (unsigned*)((char*)d_ws + 4096);       // 64 KB
    float*    cn1g    = (float*)((char*)d_ws + 4096 + 65536);  // 2 KB

    cb_prep<<<8, 512, 0, stream>>>(cb, cbBg, cn1g, counts);
    vq_main<<<NBLK, 256, 0, stream>>>(z, cbBg, cn1g, out, counts, lossArr);
    vq_final<<<1, 512, 0, stream>>>(counts, lossArr, out + NELEM);
}